// Round 1
// 1093.730 us; speedup vs baseline: 1.0110x; 1.0110x over previous
//
#include <hip/hip_runtime.h>
#include <cstdint>

#define PAD 2048
#define KG 1408   // 3*256 conv + 640 cond

typedef float f32x4 __attribute__((ext_vector_type(4)));
typedef __bf16 bf16x8 __attribute__((ext_vector_type(8)));
typedef __bf16 bf16x4 __attribute__((ext_vector_type(4)));

__device__ __forceinline__ void g2l16(const void* g, void* l) {
    __builtin_amdgcn_global_load_lds(
        (__attribute__((address_space(1))) void*)(uintptr_t)g,
        (__attribute__((address_space(3))) void*)(uint32_t)(uintptr_t)l,
        16, 0, 0);
}

// ---------------- setup kernels ----------------

// vectorized fp32 -> bf16 (4 elems/thread)
__global__ void cvt_bf16_kernel(const float4* __restrict__ src, bf16x4* __restrict__ dst, int n4) {
    int idx = blockIdx.x * 256 + threadIdx.x;
    if (idx < n4) {
        float4 v = src[idx];
        bf16x4 o = {(__bf16)v.x, (__bf16)v.y, (__bf16)v.z, (__bf16)v.w};
        dst[idx] = o;
    }
}

// whole padded started buffer: pad rows = 0, data rows = audio @ w_start + b_start. 4 ch/thread.
__global__ void init_started_kernel(const float* __restrict__ audio, const float* __restrict__ w_start,
                                    const float* __restrict__ b_start, __bf16* __restrict__ started_pad) {
    int pr = blockIdx.x * 4 + (threadIdx.x >> 6);
    int c0 = (threadIdx.x & 63) * 4;
    int off = pr & 8191;
    bf16x4 o = {(__bf16)0.f, (__bf16)0.f, (__bf16)0.f, (__bf16)0.f};
    if (off >= PAD && off < PAD + 4096) {
        int r = ((pr >> 13) << 12) + (off - PAD);
        float a0 = audio[r * 4 + 0], a1 = audio[r * 4 + 1], a2 = audio[r * 4 + 2], a3 = audio[r * 4 + 3];
        for (int j = 0; j < 4; ++j) {
            int c = c0 + j;
            o[j] = (__bf16)(b_start[c] + a0 * w_start[c] + a1 * w_start[256 + c]
                            + a2 * w_start[512 + c] + a3 * w_start[768 + c]);
        }
    }
    *(bf16x4*)&started_pad[(size_t)pr * 256 + c0] = o;
}

// Build Wg[i][n'][k] bf16 (n' interleaved by 16: tanh16/sig16 groups), k: 0-767 conv taps, 768-1407 cond
__global__ void transpose_gate(const float* __restrict__ w_in, const float* __restrict__ w_cond,
                               __bf16* __restrict__ Wg) {
    __shared__ float tile[64][65];
    int i = blockIdx.z;
    int k0 = blockIdx.y * 64, n0 = blockIdx.x * 64;
    int tid = threadIdx.x, c = tid & 63, rr = tid >> 6;
    for (int it = 0; it < 16; ++it) {
        int kl = it * 4 + rr;
        int k = k0 + kl;
        int np = n0 + c;
        int phys = ((np >> 4) & 1) * 256 + (np >> 5) * 16 + (np & 15);
        float v;
        if (k < 768) v = w_in[((i * 3 + (k >> 8)) * 256 + (k & 255)) * 512 + phys];
        else         v = w_cond[(i * 640 + (k - 768)) * 512 + phys];
        tile[kl][c] = v;
    }
    __syncthreads();
    for (int it = 0; it < 16; ++it) {
        int nl = it * 4 + rr;
        Wg[(size_t)(i * 512 + n0 + nl) * KG + k0 + c] = (__bf16)tile[c][nl];
    }
}

// generic K x N fp32 -> [N][K] bf16 transpose (tiles of 64x64)
__global__ void transpose_kn(const float* __restrict__ src, __bf16* __restrict__ dst,
                             int K, int N, int srcLS, int dstLS) {
    __shared__ float tile[64][65];
    int i = blockIdx.z;
    int k0 = blockIdx.y * 64, n0 = blockIdx.x * 64;
    int tid = threadIdx.x, c = tid & 63, rr = tid >> 6;
    const float* s = src + (size_t)i * srcLS;
    __bf16* dp = dst + (size_t)i * dstLS;
    for (int it = 0; it < 16; ++it) {
        int kl = it * 4 + rr;
        tile[kl][c] = s[(k0 + kl) * N + n0 + c];
    }
    __syncthreads();
    for (int it = 0; it < 16; ++it) {
        int nl = it * 4 + rr;
        dp[(size_t)(n0 + nl) * K + k0 + c] = (__bf16)tile[c][nl];
    }
}

__global__ void bias_gate_kernel(const float* __restrict__ b_in, const float* __restrict__ b_cond,
                                 float* __restrict__ bias) {
    int idx = blockIdx.x * 256 + threadIdx.x;   // 0..6143
    int i = idx >> 9, np = idx & 511;
    int phys = ((np >> 4) & 1) * 256 + (np >> 5) * 16 + (np & 15);
    bias[idx] = b_in[i * 512 + phys] + b_cond[i * 512 + phys];
}

// blocks 0..95: wfold[i][k][c] = sum_j w_res_skip[i][k][j] * w_end[j][c]  (i=11 uses w_res_last)
// block 96: outconst[c] = b_end[c] + (sum_i b_res_skip[i] + b_res_last) @ w_end
__global__ void wfold_kernel(const float* __restrict__ w_res, const float* __restrict__ w_res_last,
                             const float* __restrict__ w_end, const float* __restrict__ b_res,
                             const float* __restrict__ b_res_last, const float* __restrict__ b_end,
                             float* __restrict__ wfold, float* __restrict__ outconst) {
    if (blockIdx.x == 96) {
        __shared__ float red[256][8];
        int j = threadIdx.x;
        float bsum = b_res_last[j];
        for (int i = 0; i < 11; ++i) bsum += b_res[i * 512 + 256 + j];
        for (int c = 0; c < 8; ++c) red[j][c] = bsum * w_end[j * 8 + c];
        __syncthreads();
        if (j < 8) {
            float s = b_end[j];
            for (int t = 0; t < 256; ++t) s += red[t][j];
            outconst[j] = s;
        }
        return;
    }
    int idx = blockIdx.x * 256 + threadIdx.x;   // 0..24575
    int i = idx >> 11, rem = idx & 2047, k = rem >> 3, c = rem & 7;
    float s = 0.f;
    if (i < 11) {
        const float* wr = w_res + (size_t)(i * 256 + k) * 512 + 256;
        for (int j = 0; j < 256; ++j) s += wr[j] * w_end[j * 8 + c];
    } else {
        const float* wr = w_res_last + k * 256;
        for (int j = 0; j < 256; ++j) s += wr[j] * w_end[j * 8 + c];
    }
    wfold[idx] = s;
}

// ---------------- main GEMM kernels ----------------

// fused conv + cond + gate. 128x256 tile (acc 4x8/wave), LDS double-buffer,
// one barrier per k-step, single prefetch reg-set.
// LDS row stride padded 32 -> 40 elems (80B): 16-lane fragment reads advance
// 20 banks/row (period 8, all multiples of 4) -> uniform 8 touches/bank =
// conflict-free, vs 8-way conflict at 64B stride. Same for stash writes.
// Grid: x = m (fast, 256), y = n (2) so A-sharing n-blocks land on one XCD.
__global__ __launch_bounds__(256, 2) void gate_kernel(
    const __bf16* __restrict__ started_pad, const __bf16* __restrict__ spect,
    const __bf16* __restrict__ Wg,     // layer base [512][1408]
    const float* __restrict__ bias,    // layer base [512] (interleaved order)
    __bf16* __restrict__ activated, int d) {
    // SMEM: As[2][128*40] at 0 / 5120, Bs[2][256*40] at 10240 / 20480; total 30720 elems = 60KB
    __shared__ __align__(16) __bf16 SMEM[30720];
    const int tid = threadIdx.x;
    const int m0 = blockIdx.x * 128;
    const int n0 = blockIdx.y * 256;
    const int padbase = ((m0 >> 12) << 13) + PAD + (m0 & 4095);
    const int srow = tid >> 2;
    const int skq = (tid & 3) * 8;
    const int wave = tid >> 6, lane = tid & 63;
    const int wm = (wave >> 1) * 64, wn = (wave & 1) * 128;
    const int quad = lane >> 4, l15 = lane & 15;

    f32x4 acc[4][8];
    for (int i = 0; i < 4; i++)
        for (int j = 0; j < 8; j++) acc[i][j] = f32x4{0.f, 0.f, 0.f, 0.f};

    const __bf16* Bbase = Wg + (n0 + srow) * KG + skq;

    bf16x8 rA[2], rB[4];
    auto loadTile = [&](int kk) {
        const __bf16* gA0;
        int rstride;
        if (kk < 768) {
            int tap = kk >> 8;
            int koff = kk & 255;
            gA0 = started_pad + (padbase + srow + (tap - 1) * d) * 256 + koff + skq;
            rstride = 256;
        } else {
            gA0 = spect + (m0 + srow) * 640 + (kk - 768) + skq;
            rstride = 640;
        }
        rA[0] = *(const bf16x8*)gA0;
        rA[1] = *(const bf16x8*)(gA0 + 64 * rstride);
        const __bf16* gB0 = Bbase + kk;
        rB[0] = *(const bf16x8*)gB0;
        rB[1] = *(const bf16x8*)(gB0 + 64 * KG);
        rB[2] = *(const bf16x8*)(gB0 + 128 * KG);
        rB[3] = *(const bf16x8*)(gB0 + 192 * KG);
    };
    auto stash = [&](int buf) {
        __bf16* Ab = SMEM + buf * 5120;
        __bf16* Bb = SMEM + 10240 + buf * 10240;
        *(bf16x8*)&Ab[srow * 40 + skq] = rA[0];
        *(bf16x8*)&Ab[(64 + srow) * 40 + skq] = rA[1];
        *(bf16x8*)&Bb[srow * 40 + skq] = rB[0];
        *(bf16x8*)&Bb[(64 + srow) * 40 + skq] = rB[1];
        *(bf16x8*)&Bb[(128 + srow) * 40 + skq] = rB[2];
        *(bf16x8*)&Bb[(192 + srow) * 40 + skq] = rB[3];
    };

    // prologue: tile 0 -> buf0, tile 1 -> regs
    loadTile(0);
    stash(0);
    loadTile(32);
    __syncthreads();

    for (int ks = 0; ks < 44; ++ks) {
        const int cur = ks & 1, nxt = cur ^ 1;
        const __bf16* Ab = SMEM + cur * 5120;
        const __bf16* Bb = SMEM + 10240 + cur * 10240;
        bf16x8 a[4], b[8];
        for (int mi = 0; mi < 4; mi++) a[mi] = *(const bf16x8*)&Ab[(wm + mi * 16 + l15) * 40 + quad * 8];
        for (int ni = 0; ni < 8; ni++) b[ni] = *(const bf16x8*)&Bb[(wn + ni * 16 + l15) * 40 + quad * 8];
        if (ks + 1 < 44) stash(nxt);
        if (ks + 2 < 44) loadTile((ks + 2) * 32);
        for (int mi = 0; mi < 4; mi++)
            for (int ni = 0; ni < 8; ni++)
                acc[mi][ni] = __builtin_amdgcn_mfma_f32_16x16x32_bf16(a[mi], b[ni], acc[mi][ni], 0, 0, 0);
        __syncthreads();
    }

    // epilogue: gate, stage 128x128 activated channels in LDS (row stride 132), coalesced store.
    __bf16* tile = SMEM;   // 128*132 = 16896 elems <= 30720
    for (int nj = 0; nj < 4; ++nj) {
        int colT = wn + nj * 32 + l15;
        float bt = bias[n0 + colT];
        float bs = bias[n0 + colT + 16];
        int chl = (wn >> 1) + nj * 16 + l15;
        for (int mi = 0; mi < 4; ++mi) {
            for (int reg = 0; reg < 4; ++reg) {
                int row = wm + mi * 16 + quad * 4 + reg;
                float xt = acc[mi][2 * nj][reg] + bt;
                float xs = acc[mi][2 * nj + 1][reg] + bs;
                float th = 2.f / (1.f + __expf(-2.f * xt)) - 1.f;
                float sg = 1.f / (1.f + __expf(-xs));
                tile[row * 132 + chl] = (__bf16)(th * sg);
            }
        }
    }
    __syncthreads();
    int chb = n0 >> 1;
    for (int pass = 0; pass < 8; ++pass) {
        int row = (tid >> 4) + 16 * pass;
        int seg = tid & 15;
        bf16x8 v = *(const bf16x8*)&tile[row * 132 + seg * 8];
        *(bf16x8*)&activated[(m0 + row) * 256 + chb + seg * 8] = v;
    }
}

// rs_res = activated @ Wr + b_res ; started_pad += rs_res (bf16 RMW)
// Grid (256,2): x = m (fast) so the reader of m-tile x sits on the XCD that produced it.
// Blocks with blockIdx.y==0 also run out += activated @ wfold via MFMA (bf16 wfold,
// 16-col B-extension in LDS; waves with wn==0 cover all 128 rows).
__global__ __launch_bounds__(256) void res_kernel(
    const __bf16* __restrict__ activated, const __bf16* __restrict__ Wr,  // [256][256]
    const float* __restrict__ b_res,      // layer base (first 256 cols used)
    const float* __restrict__ wfold,      // layer base [256][8] fp32
    const float* __restrict__ outconst,
    __bf16* __restrict__ started_pad, float* __restrict__ out, int initOut) {
    __shared__ __align__(16) __bf16 As[128 * 32];
    __shared__ __align__(16) __bf16 Bs[128 * 32];
    __shared__ __align__(16) __bf16 WfB[16 * 264];   // [col][k], cols 8..15 zero, padded stride
    const int tid = threadIdx.x;
    const int m0 = blockIdx.x * 128;
    const int n0 = blockIdx.y * 128;
    const int srow = tid >> 2;
    const int skq = (tid & 3) * 8;
    const int wave = tid >> 6, lane = tid & 63;
    const int wm = (wave >> 1) * 64, wn = (wave & 1) * 64;
    const int quad = lane >> 4, l15 = lane & 15;
    const bool doOut = (blockIdx.y == 0);
    const bool outWave = doOut && (wn == 0);

    f32x4 acc[4][4];
    for (int i = 0; i < 4; i++)
        for (int j = 0; j < 4; j++) acc[i][j] = f32x4{0.f, 0.f, 0.f, 0.f};
    f32x4 acc_o[4];
    for (int i = 0; i < 4; i++) acc_o[i] = f32x4{0.f, 0.f, 0.f, 0.f};

    const __bf16* Abase = activated + (m0 + srow) * 256 + skq;
    const __bf16* Bbase = Wr + (n0 + srow) * 256 + skq;

    if (doOut) {
        // stage wfold bf16 [16 cols][256 k] (cols 8..15 = 0)
        for (int t = 0; t < 16; ++t) {
            int e = t * 256 + tid;          // 0..4095
            int col = e >> 8, k = e & 255;
            WfB[col * 264 + k] = (col < 8) ? (__bf16)wfold[k * 8 + col] : (__bf16)0.f;
        }
    }

    for (int ks = 0; ks < 8; ++ks) {
        int kk = ks * 32;
        g2l16(Abase + kk, &As[srow * 32 + skq]);
        g2l16(Abase + kk + 64 * 256, &As[(64 + srow) * 32 + skq]);
        g2l16(Bbase + kk, &Bs[srow * 32 + skq]);
        g2l16(Bbase + kk + 64 * 256, &Bs[(64 + srow) * 32 + skq]);
        __syncthreads();
        bf16x8 a[4], b[4];
        for (int mi = 0; mi < 4; mi++) a[mi] = *(const bf16x8*)&As[(wm + mi * 16 + l15) * 32 + quad * 8];
        for (int ni = 0; ni < 4; ni++) b[ni] = *(const bf16x8*)&Bs[(wn + ni * 16 + l15) * 32 + quad * 8];
        for (int mi = 0; mi < 4; mi++)
            for (int ni = 0; ni < 4; ni++)
                acc[mi][ni] = __builtin_amdgcn_mfma_f32_16x16x32_bf16(a[mi], b[ni], acc[mi][ni], 0, 0, 0);
        if (outWave) {
            bf16x8 bx = *(const bf16x8*)&WfB[l15 * 264 + kk + quad * 8];
            for (int mi = 0; mi < 4; mi++)
                acc_o[mi] = __builtin_amdgcn_mfma_f32_16x16x32_bf16(a[mi], bx, acc_o[mi], 0, 0, 0);
        }
        __syncthreads();
    }

    for (int ni = 0; ni < 4; ++ni) {
        int col = n0 + wn + ni * 16 + l15;
        float bcol = b_res[col];
        for (int mi = 0; mi < 4; ++mi) {
            for (int reg = 0; reg < 4; ++reg) {
                int r = m0 + wm + mi * 16 + quad * 4 + reg;
                int pr = ((r >> 12) << 13) + PAD + (r & 4095);
                int idx = pr * 256 + col;
                float f = (float)started_pad[idx] + acc[mi][ni][reg] + bcol;
                started_pad[idx] = (__bf16)f;
            }
        }
    }
    if (outWave && l15 < 8) {
        for (int mi = 0; mi < 4; ++mi) {
            for (int reg = 0; reg < 4; ++reg) {
                int r = m0 + wm + mi * 16 + quad * 4 + reg;
                float base = initOut ? outconst[l15] : out[r * 8 + l15];
                out[r * 8 + l15] = base + acc_o[mi][reg];
            }
        }
    }
}

// last layer: out += activated @ wfold[11]  (no res half). Grid x = m (XCD-aligned).
__global__ __launch_bounds__(256) void outacc_kernel(
    const __bf16* __restrict__ activated, const float* __restrict__ wfold,
    float* __restrict__ out) {
    __shared__ __align__(16) float Wf[2048];
    int tid = threadIdx.x;
    ((float4*)Wf)[tid] = ((const float4*)wfold)[tid];
    ((float4*)Wf)[256 + tid] = ((const float4*)wfold)[256 + tid];
    __syncthreads();
    int row2 = tid >> 1, half = tid & 1;
    int r = blockIdx.x * 128 + row2;
    const bf16x8* ap = (const bf16x8*)(activated + r * 256);
    const float4* wf = (const float4*)Wf;
    float ox = 0.f, oy = 0.f, oz = 0.f, ow = 0.f;
    for (int c8 = 0; c8 < 32; ++c8) {
        bf16x8 av = ap[c8];
        for (int e = 0; e < 8; ++e) {
            float a = (float)av[e];
            float4 w = wf[(c8 * 8 + e) * 2 + half];
            ox += a * w.x; oy += a * w.y; oz += a * w.z; ow += a * w.w;
        }
    }
    float4* op = (float4*)&out[r * 8 + half * 4];
    float4 o = *op;
    o.x += ox; o.y += oy; o.z += oz; o.w += ow;
    *op = o;
}

// ---------------- launch ----------------

extern "C" void kernel_launch(void* const* d_in, const int* in_sizes, int n_in,
                              void* d_out, int out_size, void* d_ws, size_t ws_size,
                              hipStream_t stream) {
    const float* audio      = (const float*)d_in[0];
    const float* spect      = (const float*)d_in[1];
    const float* w_start    = (const float*)d_in[2];
    const float* b_start    = (const float*)d_in[3];
    const float* w_in       = (const float*)d_in[4];
    const float* b_in       = (const float*)d_in[5];
    const float* w_cond     = (const float*)d_in[6];
    const float* b_cond     = (const float*)d_in[7];
    const float* w_res      = (const float*)d_in[8];
    const float* b_res      = (const float*)d_in[9];
    const float* w_res_last = (const float*)d_in[10];
    const float* b_res_last = (const float*)d_in[11];
    const float* w_end      = (const float*)d_in[12];
    const float* b_end      = (const float*)d_in[13];
    float* out = (float*)d_out;

    char* ws = (char*)d_ws;
    __bf16* started_pad = (__bf16*)ws; ws += 33554432;   // 65536 x 256 bf16 (padded)
    __bf16* activated   = (__bf16*)ws; ws += 16777216;   // 32768 x 256 bf16
    __bf16* spect_bf    = (__bf16*)ws; ws += 41943040;   // 32768 x 640 bf16
    __bf16* Wg          = (__bf16*)ws; ws += 17301504;   // 12 x 512 x 1408 bf16
    __bf16* Wr          = (__bf16*)ws; ws += 1441792;    // 11 x 256 x 256 bf16 (res half, [n][k])
    float*  wfold       = (float*)ws;  ws += 98304;      // 12 x 256 x 8 f32
    float*  biasg       = (float*)ws;  ws += 24576;      // 12 x 512 f32
    float*  outconst    = (float*)ws;  ws += 256;        // 8 f32

    init_started_kernel<<<dim3(16384), 256, 0, stream>>>(audio, w_start, b_start, started_pad);
    cvt_bf16_kernel<<<dim3(20480), 256, 0, stream>>>((const float4*)spect, (bf16x4*)spect_bf, 5242880);
    transpose_gate<<<dim3(8, 22, 12), 256, 0, stream>>>(w_in, w_cond, Wg);
    transpose_kn<<<dim3(4, 4, 11), 256, 0, stream>>>(w_res, Wr, 256, 512, 256 * 512, 256 * 256);
    bias_gate_kernel<<<dim3(24), 256, 0, stream>>>(b_in, b_cond, biasg);
    wfold_kernel<<<dim3(97), 256, 0, stream>>>(w_res, w_res_last, w_end, b_res, b_res_last, b_end,
                                               wfold, outconst);

    for (int i = 0; i < 12; ++i) {
        gate_kernel<<<dim3(256, 2), 256, 0, stream>>>(
            started_pad, spect_bf, Wg + (size_t)i * 512 * KG, biasg + i * 512, activated, 1 << i);
        if (i < 11) {
            res_kernel<<<dim3(256, 2), 256, 0, stream>>>(
                activated, Wr + (size_t)i * 256 * 256, b_res + i * 512,
                wfold + i * 2048, outconst, started_pad, out, i == 0 ? 1 : 0);
        } else {
            outacc_kernel<<<dim3(256), 256, 0, stream>>>(activated, wfold + 11 * 2048, out);
        }
    }
}

// Round 2
// 1056.229 us; speedup vs baseline: 1.0469x; 1.0355x over previous
//
#include <hip/hip_runtime.h>
#include <cstdint>

#define PAD 2048
#define KG 1408   // 3*256 conv + 640 cond

typedef float f32x4 __attribute__((ext_vector_type(4)));
typedef __bf16 bf16x8 __attribute__((ext_vector_type(8)));
typedef __bf16 bf16x4 __attribute__((ext_vector_type(4)));

__device__ __forceinline__ void g2l16(const void* g, void* l) {
    __builtin_amdgcn_global_load_lds(
        (__attribute__((address_space(1))) void*)(uintptr_t)g,
        (__attribute__((address_space(3))) void*)(uint32_t)(uintptr_t)l,
        16, 0, 0);
}

// ---------------- setup kernels ----------------

// vectorized fp32 -> bf16 (4 elems/thread)
__global__ void cvt_bf16_kernel(const float4* __restrict__ src, bf16x4* __restrict__ dst, int n4) {
    int idx = blockIdx.x * 256 + threadIdx.x;
    if (idx < n4) {
        float4 v = src[idx];
        bf16x4 o = {(__bf16)v.x, (__bf16)v.y, (__bf16)v.z, (__bf16)v.w};
        dst[idx] = o;
    }
}

// whole padded started buffer: pad rows = 0, data rows = audio @ w_start + b_start. 4 ch/thread.
__global__ void init_started_kernel(const float* __restrict__ audio, const float* __restrict__ w_start,
                                    const float* __restrict__ b_start, __bf16* __restrict__ started_pad) {
    int pr = blockIdx.x * 4 + (threadIdx.x >> 6);
    int c0 = (threadIdx.x & 63) * 4;
    int off = pr & 8191;
    bf16x4 o = {(__bf16)0.f, (__bf16)0.f, (__bf16)0.f, (__bf16)0.f};
    if (off >= PAD && off < PAD + 4096) {
        int r = ((pr >> 13) << 12) + (off - PAD);
        float a0 = audio[r * 4 + 0], a1 = audio[r * 4 + 1], a2 = audio[r * 4 + 2], a3 = audio[r * 4 + 3];
        for (int j = 0; j < 4; ++j) {
            int c = c0 + j;
            o[j] = (__bf16)(b_start[c] + a0 * w_start[c] + a1 * w_start[256 + c]
                            + a2 * w_start[512 + c] + a3 * w_start[768 + c]);
        }
    }
    *(bf16x4*)&started_pad[(size_t)pr * 256 + c0] = o;
}

// Build Wg[i][n'][k] bf16 (n' interleaved by 16: tanh16/sig16 groups), k: 0-767 conv taps, 768-1407 cond
__global__ void transpose_gate(const float* __restrict__ w_in, const float* __restrict__ w_cond,
                               __bf16* __restrict__ Wg) {
    __shared__ float tile[64][65];
    int i = blockIdx.z;
    int k0 = blockIdx.y * 64, n0 = blockIdx.x * 64;
    int tid = threadIdx.x, c = tid & 63, rr = tid >> 6;
    for (int it = 0; it < 16; ++it) {
        int kl = it * 4 + rr;
        int k = k0 + kl;
        int np = n0 + c;
        int phys = ((np >> 4) & 1) * 256 + (np >> 5) * 16 + (np & 15);
        float v;
        if (k < 768) v = w_in[((i * 3 + (k >> 8)) * 256 + (k & 255)) * 512 + phys];
        else         v = w_cond[(i * 640 + (k - 768)) * 512 + phys];
        tile[kl][c] = v;
    }
    __syncthreads();
    for (int it = 0; it < 16; ++it) {
        int nl = it * 4 + rr;
        Wg[(size_t)(i * 512 + n0 + nl) * KG + k0 + c] = (__bf16)tile[c][nl];
    }
}

// generic K x N fp32 -> [N][K] bf16 transpose (tiles of 64x64)
__global__ void transpose_kn(const float* __restrict__ src, __bf16* __restrict__ dst,
                             int K, int N, int srcLS, int dstLS) {
    __shared__ float tile[64][65];
    int i = blockIdx.z;
    int k0 = blockIdx.y * 64, n0 = blockIdx.x * 64;
    int tid = threadIdx.x, c = tid & 63, rr = tid >> 6;
    const float* s = src + (size_t)i * srcLS;
    __bf16* dp = dst + (size_t)i * dstLS;
    for (int it = 0; it < 16; ++it) {
        int kl = it * 4 + rr;
        tile[kl][c] = s[(k0 + kl) * N + n0 + c];
    }
    __syncthreads();
    for (int it = 0; it < 16; ++it) {
        int nl = it * 4 + rr;
        dp[(size_t)(n0 + nl) * K + k0 + c] = (__bf16)tile[c][nl];
    }
}

__global__ void bias_gate_kernel(const float* __restrict__ b_in, const float* __restrict__ b_cond,
                                 float* __restrict__ bias) {
    int idx = blockIdx.x * 256 + threadIdx.x;   // 0..6143
    int i = idx >> 9, np = idx & 511;
    int phys = ((np >> 4) & 1) * 256 + (np >> 5) * 16 + (np & 15);
    bias[idx] = b_in[i * 512 + phys] + b_cond[i * 512 + phys];
}

// blocks 0..95: wfold[i][k][c] = sum_j w_res_skip[i][k][j] * w_end[j][c]  (i=11 uses w_res_last)
// block 96: outconst[c] = b_end[c] + (sum_i b_res_skip[i] + b_res_last) @ w_end
__global__ void wfold_kernel(const float* __restrict__ w_res, const float* __restrict__ w_res_last,
                             const float* __restrict__ w_end, const float* __restrict__ b_res,
                             const float* __restrict__ b_res_last, const float* __restrict__ b_end,
                             float* __restrict__ wfold, float* __restrict__ outconst) {
    if (blockIdx.x == 96) {
        __shared__ float red[256][8];
        int j = threadIdx.x;
        float bsum = b_res_last[j];
        for (int i = 0; i < 11; ++i) bsum += b_res[i * 512 + 256 + j];
        for (int c = 0; c < 8; ++c) red[j][c] = bsum * w_end[j * 8 + c];
        __syncthreads();
        if (j < 8) {
            float s = b_end[j];
            for (int t = 0; t < 256; ++t) s += red[t][j];
            outconst[j] = s;
        }
        return;
    }
    int idx = blockIdx.x * 256 + threadIdx.x;   // 0..24575
    int i = idx >> 11, rem = idx & 2047, k = rem >> 3, c = rem & 7;
    float s = 0.f;
    if (i < 11) {
        const float* wr = w_res + (size_t)(i * 256 + k) * 512 + 256;
        for (int j = 0; j < 256; ++j) s += wr[j] * w_end[j * 8 + c];
    } else {
        const float* wr = w_res_last + k * 256;
        for (int j = 0; j < 256; ++j) s += wr[j] * w_end[j * 8 + c];
    }
    wfold[idx] = s;
}

// ---------------- main GEMM kernels ----------------

// fused conv + cond + gate. 256x256 tile, 512 threads (8 waves, 2m x 4n),
// BK=32, ring of 4 LDS slots (128KB), global_load_lds staged 2 tiles ahead,
// counted s_waitcnt vmcnt(4) (never 0 in steady state), raw s_barrier,
// setprio(1) around MFMA clusters. In-row XOR swizzle (col ^= ((row>>1)&3)*8)
// applied inversely on the global source, forward on fragment ds_reads.
// Grid: x = m (128), y = n (2); pair (x,0)/(x,1) differ by 128 in linear id
// -> same XCD -> A-tile fetched once per XCD.
__global__ __launch_bounds__(512, 2) void gate_kernel(
    const __bf16* __restrict__ started_pad, const __bf16* __restrict__ spect,
    const __bf16* __restrict__ Wg,     // layer base [512][1408]
    const float* __restrict__ bias,    // layer base [512] (interleaved order)
    __bf16* __restrict__ activated, int d) {
    // LDS: A slots s*8192 elems (s=0..3), B slots 32768 + s*8192. 65536 elems = 128KB.
    __shared__ __align__(16) __bf16 SMEM[65536];
    const int tid = threadIdx.x;
    const int m0 = blockIdx.x * 256;
    const int n0 = blockIdx.y * 256;
    const int padbase = ((m0 >> 12) << 13) + PAD + (m0 & 4095);
    const int wave = tid >> 6, lane = tid & 63;
    const int wr = wave >> 2, wc = wave & 3;          // 2 m-rows x 4 n-cols of waves
    const int quad = lane >> 4, l15 = lane & 15;

    // staging geometry: thread covers 16B at (row = op*128 + (tid>>2), col 16B-slot tid&3)
    const int srow = tid >> 2;                                        // 0..127
    const int scw = ((tid & 3) * 8) ^ (((tid >> 3) & 3) << 3);        // pre-swizzled col (elems)

    f32x4 acc[8][4];
    #pragma unroll
    for (int i = 0; i < 8; i++)
        #pragma unroll
        for (int j = 0; j < 4; j++) acc[i][j] = f32x4{0.f, 0.f, 0.f, 0.f};

    auto stageA = [&](int kt, int s) {
        const __bf16* g0;
        int rs;
        if (kt < 24) {                       // conv taps: 8 tiles per tap
            int tap = kt >> 3;
            int cb = (kt & 7) * 32;
            g0 = started_pad + (padbase + (tap - 1) * d) * 256 + cb + scw;
            rs = 256;
        } else {                             // cond: spect cols
            int cb = (kt - 24) * 32;
            g0 = spect + (size_t)m0 * 640 + cb + scw;
            rs = 640;
        }
        __bf16* As = SMEM + s * 8192;
        g2l16(g0 + srow * rs, As + tid * 8);
        g2l16(g0 + (128 + srow) * rs, As + 4096 + tid * 8);
    };
    auto stageB = [&](int kt, int s) {
        const __bf16* g0 = Wg + (size_t)(n0 + srow) * KG + kt * 32 + scw;
        __bf16* Bs = SMEM + 32768 + s * 8192;
        g2l16(g0, Bs + tid * 8);
        g2l16(g0 + 128 * KG, Bs + 4096 + tid * 8);
    };

    // prologue: tiles 0 and 1 staged; wait tile 0 (leave tile 1 in flight)
    stageA(0, 0); stageB(0, 0);
    stageA(1, 1); stageB(1, 1);
    asm volatile("s_waitcnt vmcnt(4)" ::: "memory");
    __builtin_amdgcn_s_barrier();

    for (int j = 0; j < 44; ++j) {
        const int s = j & 3;
        const __bf16* Asl = SMEM + s * 8192;
        const __bf16* Bsl = SMEM + 32768 + s * 8192;

        bf16x8 b[4];
        #pragma unroll
        for (int nf = 0; nf < 4; ++nf) {
            int br = wc * 64 + nf * 16 + l15;
            b[nf] = *(const bf16x8*)&Bsl[br * 32 + ((quad * 8) ^ (((br >> 1) & 3) << 3))];
        }
        // ---- phase 0: m-half 0 ----
        bf16x8 a[4];
        #pragma unroll
        for (int f = 0; f < 4; ++f) {
            int ar = wr * 128 + f * 16 + l15;
            a[f] = *(const bf16x8*)&Asl[ar * 32 + ((quad * 8) ^ (((ar >> 1) & 3) << 3))];
        }
        if (j + 2 < 44) stageA(j + 2, (j + 2) & 3);
        __builtin_amdgcn_s_barrier();
        __builtin_amdgcn_s_setprio(1);
        #pragma unroll
        for (int f = 0; f < 4; ++f)
            #pragma unroll
            for (int nf = 0; nf < 4; ++nf)
                acc[f][nf] = __builtin_amdgcn_mfma_f32_16x16x32_bf16(a[f], b[nf], acc[f][nf], 0, 0, 0);
        __builtin_amdgcn_s_setprio(0);
        __builtin_amdgcn_s_barrier();
        // ---- phase 1: m-half 1 ----
        #pragma unroll
        for (int f = 0; f < 4; ++f) {
            int ar = wr * 128 + 64 + f * 16 + l15;
            a[f] = *(const bf16x8*)&Asl[ar * 32 + ((quad * 8) ^ (((ar >> 1) & 3) << 3))];
        }
        if (j + 2 < 44) stageB(j + 2, (j + 2) & 3);
        if (j + 1 < 44) {
            if (j + 2 < 44) asm volatile("s_waitcnt vmcnt(4)" ::: "memory");
            else            asm volatile("s_waitcnt vmcnt(0)" ::: "memory");
        }
        __builtin_amdgcn_s_barrier();
        __builtin_amdgcn_s_setprio(1);
        #pragma unroll
        for (int f = 0; f < 4; ++f)
            #pragma unroll
            for (int nf = 0; nf < 4; ++nf)
                acc[4 + f][nf] = __builtin_amdgcn_mfma_f32_16x16x32_bf16(a[f], b[nf], acc[4 + f][nf], 0, 0, 0);
        __builtin_amdgcn_s_setprio(0);
        __builtin_amdgcn_s_barrier();
    }

    // epilogue: gate, stage 256x128 activated channels in LDS (row stride 132), coalesced store.
    __bf16* tile = SMEM;   // 256*132 = 33792 elems <= 65536
    #pragma unroll
    for (int nj = 0; nj < 2; ++nj) {
        int colT = wc * 64 + nj * 32 + l15;
        float bt = bias[n0 + colT];
        float bs = bias[n0 + colT + 16];
        int chl = wc * 32 + nj * 16 + l15;
        #pragma unroll
        for (int mi = 0; mi < 8; ++mi) {
            #pragma unroll
            for (int reg = 0; reg < 4; ++reg) {
                int row = wr * 128 + mi * 16 + quad * 4 + reg;
                float xt = acc[mi][2 * nj][reg] + bt;
                float xs = acc[mi][2 * nj + 1][reg] + bs;
                float th = 2.f / (1.f + __expf(-2.f * xt)) - 1.f;
                float sg = 1.f / (1.f + __expf(-xs));
                tile[row * 132 + chl] = (__bf16)(th * sg);
            }
        }
    }
    __syncthreads();
    int chb = n0 >> 1;
    for (int pass = 0; pass < 8; ++pass) {
        int row = (tid >> 4) + 32 * pass;
        int seg = tid & 15;
        bf16x8 v = *(const bf16x8*)&tile[row * 132 + seg * 8];
        *(bf16x8*)&activated[(m0 + row) * 256 + chb + seg * 8] = v;
    }
}

// rs_res = activated @ Wr + b_res ; started_pad += rs_res (bf16 RMW)
// Grid (256,2): x = m (fast) so the reader of m-tile x sits on the XCD that produced it.
// Blocks with blockIdx.y==0 also run out += activated @ wfold via MFMA (bf16 wfold,
// 16-col B-extension in LDS; waves with wn==0 cover all 128 rows).
__global__ __launch_bounds__(256) void res_kernel(
    const __bf16* __restrict__ activated, const __bf16* __restrict__ Wr,  // [256][256]
    const float* __restrict__ b_res,      // layer base (first 256 cols used)
    const float* __restrict__ wfold,      // layer base [256][8] fp32
    const float* __restrict__ outconst,
    __bf16* __restrict__ started_pad, float* __restrict__ out, int initOut) {
    __shared__ __align__(16) __bf16 As[128 * 32];
    __shared__ __align__(16) __bf16 Bs[128 * 32];
    __shared__ __align__(16) __bf16 WfB[16 * 264];   // [col][k], cols 8..15 zero, padded stride
    const int tid = threadIdx.x;
    const int m0 = blockIdx.x * 128;
    const int n0 = blockIdx.y * 128;
    const int srow = tid >> 2;
    const int skq = (tid & 3) * 8;
    const int wave = tid >> 6, lane = tid & 63;
    const int wm = (wave >> 1) * 64, wn = (wave & 1) * 64;
    const int quad = lane >> 4, l15 = lane & 15;
    const bool doOut = (blockIdx.y == 0);
    const bool outWave = doOut && (wn == 0);

    f32x4 acc[4][4];
    for (int i = 0; i < 4; i++)
        for (int j = 0; j < 4; j++) acc[i][j] = f32x4{0.f, 0.f, 0.f, 0.f};
    f32x4 acc_o[4];
    for (int i = 0; i < 4; i++) acc_o[i] = f32x4{0.f, 0.f, 0.f, 0.f};

    const __bf16* Abase = activated + (m0 + srow) * 256 + skq;
    const __bf16* Bbase = Wr + (n0 + srow) * 256 + skq;

    if (doOut) {
        // stage wfold bf16 [16 cols][256 k] (cols 8..15 = 0)
        for (int t = 0; t < 16; ++t) {
            int e = t * 256 + tid;          // 0..4095
            int col = e >> 8, k = e & 255;
            WfB[col * 264 + k] = (col < 8) ? (__bf16)wfold[k * 8 + col] : (__bf16)0.f;
        }
    }

    for (int ks = 0; ks < 8; ++ks) {
        int kk = ks * 32;
        g2l16(Abase + kk, &As[srow * 32 + skq]);
        g2l16(Abase + kk + 64 * 256, &As[(64 + srow) * 32 + skq]);
        g2l16(Bbase + kk, &Bs[srow * 32 + skq]);
        g2l16(Bbase + kk + 64 * 256, &Bs[(64 + srow) * 32 + skq]);
        __syncthreads();
        bf16x8 a[4], b[4];
        for (int mi = 0; mi < 4; mi++) a[mi] = *(const bf16x8*)&As[(wm + mi * 16 + l15) * 32 + quad * 8];
        for (int ni = 0; ni < 4; ni++) b[ni] = *(const bf16x8*)&Bs[(wn + ni * 16 + l15) * 32 + quad * 8];
        for (int mi = 0; mi < 4; mi++)
            for (int ni = 0; ni < 4; ni++)
                acc[mi][ni] = __builtin_amdgcn_mfma_f32_16x16x32_bf16(a[mi], b[ni], acc[mi][ni], 0, 0, 0);
        if (outWave) {
            bf16x8 bx = *(const bf16x8*)&WfB[l15 * 264 + kk + quad * 8];
            for (int mi = 0; mi < 4; mi++)
                acc_o[mi] = __builtin_amdgcn_mfma_f32_16x16x32_bf16(a[mi], bx, acc_o[mi], 0, 0, 0);
        }
        __syncthreads();
    }

    for (int ni = 0; ni < 4; ++ni) {
        int col = n0 + wn + ni * 16 + l15;
        float bcol = b_res[col];
        for (int mi = 0; mi < 4; ++mi) {
            for (int reg = 0; reg < 4; ++reg) {
                int r = m0 + wm + mi * 16 + quad * 4 + reg;
                int pr = ((r >> 12) << 13) + PAD + (r & 4095);
                int idx = pr * 256 + col;
                float f = (float)started_pad[idx] + acc[mi][ni][reg] + bcol;
                started_pad[idx] = (__bf16)f;
            }
        }
    }
    if (outWave && l15 < 8) {
        for (int mi = 0; mi < 4; ++mi) {
            for (int reg = 0; reg < 4; ++reg) {
                int r = m0 + wm + mi * 16 + quad * 4 + reg;
                float base = initOut ? outconst[l15] : out[r * 8 + l15];
                out[r * 8 + l15] = base + acc_o[mi][reg];
            }
        }
    }
}

// last layer: out += activated @ wfold[11]  (no res half). Grid x = m (XCD-aligned).
__global__ __launch_bounds__(256) void outacc_kernel(
    const __bf16* __restrict__ activated, const float* __restrict__ wfold,
    float* __restrict__ out) {
    __shared__ __align__(16) float Wf[2048];
    int tid = threadIdx.x;
    ((float4*)Wf)[tid] = ((const float4*)wfold)[tid];
    ((float4*)Wf)[256 + tid] = ((const float4*)wfold)[256 + tid];
    __syncthreads();
    int row2 = tid >> 1, half = tid & 1;
    int r = blockIdx.x * 128 + row2;
    const bf16x8* ap = (const bf16x8*)(activated + r * 256);
    const float4* wf = (const float4*)Wf;
    float ox = 0.f, oy = 0.f, oz = 0.f, ow = 0.f;
    for (int c8 = 0; c8 < 32; ++c8) {
        bf16x8 av = ap[c8];
        for (int e = 0; e < 8; ++e) {
            float a = (float)av[e];
            float4 w = wf[(c8 * 8 + e) * 2 + half];
            ox += a * w.x; oy += a * w.y; oz += a * w.z; ow += a * w.w;
        }
    }
    float4* op = (float4*)&out[r * 8 + half * 4];
    float4 o = *op;
    o.x += ox; o.y += oy; o.z += oz; o.w += ow;
    *op = o;
}

// ---------------- launch ----------------

extern "C" void kernel_launch(void* const* d_in, const int* in_sizes, int n_in,
                              void* d_out, int out_size, void* d_ws, size_t ws_size,
                              hipStream_t stream) {
    const float* audio      = (const float*)d_in[0];
    const float* spect      = (const float*)d_in[1];
    const float* w_start    = (const float*)d_in[2];
    const float* b_start    = (const float*)d_in[3];
    const float* w_in       = (const float*)d_in[4];
    const float* b_in       = (const float*)d_in[5];
    const float* w_cond     = (const float*)d_in[6];
    const float* b_cond     = (const float*)d_in[7];
    const float* w_res      = (const float*)d_in[8];
    const float* b_res      = (const float*)d_in[9];
    const float* w_res_last = (const float*)d_in[10];
    const float* b_res_last = (const float*)d_in[11];
    const float* w_end      = (const float*)d_in[12];
    const float* b_end      = (const float*)d_in[13];
    float* out = (float*)d_out;

    char* ws = (char*)d_ws;
    __bf16* started_pad = (__bf16*)ws; ws += 33554432;   // 65536 x 256 bf16 (padded)
    __bf16* activated   = (__bf16*)ws; ws += 16777216;   // 32768 x 256 bf16
    __bf16* spect_bf    = (__bf16*)ws; ws += 41943040;   // 32768 x 640 bf16
    __bf16* Wg          = (__bf16*)ws; ws += 17301504;   // 12 x 512 x 1408 bf16
    __bf16* Wr          = (__bf16*)ws; ws += 1441792;    // 11 x 256 x 256 bf16 (res half, [n][k])
    float*  wfold       = (float*)ws;  ws += 98304;      // 12 x 256 x 8 f32
    float*  biasg       = (float*)ws;  ws += 24576;      // 12 x 512 f32
    float*  outconst    = (float*)ws;  ws += 256;        // 8 f32

    init_started_kernel<<<dim3(16384), 256, 0, stream>>>(audio, w_start, b_start, started_pad);
    cvt_bf16_kernel<<<dim3(20480), 256, 0, stream>>>((const float4*)spect, (bf16x4*)spect_bf, 5242880);
    transpose_gate<<<dim3(8, 22, 12), 256, 0, stream>>>(w_in, w_cond, Wg);
    transpose_kn<<<dim3(4, 4, 11), 256, 0, stream>>>(w_res, Wr, 256, 512, 256 * 512, 256 * 256);
    bias_gate_kernel<<<dim3(24), 256, 0, stream>>>(b_in, b_cond, biasg);
    wfold_kernel<<<dim3(97), 256, 0, stream>>>(w_res, w_res_last, w_end, b_res, b_res_last, b_end,
                                               wfold, outconst);

    for (int i = 0; i < 12; ++i) {
        gate_kernel<<<dim3(128, 2), 512, 0, stream>>>(
            started_pad, spect_bf, Wg + (size_t)i * 512 * KG, biasg + i * 512, activated, 1 << i);
        if (i < 11) {
            res_kernel<<<dim3(256, 2), 256, 0, stream>>>(
                activated, Wr + (size_t)i * 256 * 256, b_res + i * 512,
                wfold + i * 2048, outconst, started_pad, out, i == 0 ? 1 : 0);
        } else {
            outacc_kernel<<<dim3(256), 256, 0, stream>>>(activated, wfold + 11 * 2048, out);
        }
    }
}

// Round 3
// 1035.999 us; speedup vs baseline: 1.0673x; 1.0195x over previous
//
#include <hip/hip_runtime.h>
#include <cstdint>

#define PAD 2048
#define KG 1408   // 3*256 conv + 640 cond

typedef float f32x4 __attribute__((ext_vector_type(4)));
typedef __bf16 bf16x8 __attribute__((ext_vector_type(8)));
typedef __bf16 bf16x4 __attribute__((ext_vector_type(4)));

__device__ __forceinline__ void g2l16(const void* g, void* l) {
    __builtin_amdgcn_global_load_lds(
        (__attribute__((address_space(1))) void*)(uintptr_t)g,
        (__attribute__((address_space(3))) void*)(uint32_t)(uintptr_t)l,
        16, 0, 0);
}

// ---------------- setup kernels ----------------

// vectorized fp32 -> bf16 (4 elems/thread)
__global__ void cvt_bf16_kernel(const float4* __restrict__ src, bf16x4* __restrict__ dst, int n4) {
    int idx = blockIdx.x * 256 + threadIdx.x;
    if (idx < n4) {
        float4 v = src[idx];
        bf16x4 o = {(__bf16)v.x, (__bf16)v.y, (__bf16)v.z, (__bf16)v.w};
        dst[idx] = o;
    }
}

// whole padded started buffer: pad rows = 0, data rows = audio @ w_start + b_start. 4 ch/thread.
__global__ void init_started_kernel(const float* __restrict__ audio, const float* __restrict__ w_start,
                                    const float* __restrict__ b_start, __bf16* __restrict__ started_pad) {
    int pr = blockIdx.x * 4 + (threadIdx.x >> 6);
    int c0 = (threadIdx.x & 63) * 4;
    int off = pr & 8191;
    bf16x4 o = {(__bf16)0.f, (__bf16)0.f, (__bf16)0.f, (__bf16)0.f};
    if (off >= PAD && off < PAD + 4096) {
        int r = ((pr >> 13) << 12) + (off - PAD);
        float a0 = audio[r * 4 + 0], a1 = audio[r * 4 + 1], a2 = audio[r * 4 + 2], a3 = audio[r * 4 + 3];
        for (int j = 0; j < 4; ++j) {
            int c = c0 + j;
            o[j] = (__bf16)(b_start[c] + a0 * w_start[c] + a1 * w_start[256 + c]
                            + a2 * w_start[512 + c] + a3 * w_start[768 + c]);
        }
    }
    *(bf16x4*)&started_pad[(size_t)pr * 256 + c0] = o;
}

// Build Wg[i][n'][k] bf16 (n' interleaved by 16: tanh16/sig16 groups), k: 0-767 conv taps, 768-1407 cond
__global__ void transpose_gate(const float* __restrict__ w_in, const float* __restrict__ w_cond,
                               __bf16* __restrict__ Wg) {
    __shared__ float tile[64][65];
    int i = blockIdx.z;
    int k0 = blockIdx.y * 64, n0 = blockIdx.x * 64;
    int tid = threadIdx.x, c = tid & 63, rr = tid >> 6;
    for (int it = 0; it < 16; ++it) {
        int kl = it * 4 + rr;
        int k = k0 + kl;
        int np = n0 + c;
        int phys = ((np >> 4) & 1) * 256 + (np >> 5) * 16 + (np & 15);
        float v;
        if (k < 768) v = w_in[((i * 3 + (k >> 8)) * 256 + (k & 255)) * 512 + phys];
        else         v = w_cond[(i * 640 + (k - 768)) * 512 + phys];
        tile[kl][c] = v;
    }
    __syncthreads();
    for (int it = 0; it < 16; ++it) {
        int nl = it * 4 + rr;
        Wg[(size_t)(i * 512 + n0 + nl) * KG + k0 + c] = (__bf16)tile[c][nl];
    }
}

// generic K x N fp32 -> [N][K] bf16 transpose (tiles of 64x64)
__global__ void transpose_kn(const float* __restrict__ src, __bf16* __restrict__ dst,
                             int K, int N, int srcLS, int dstLS) {
    __shared__ float tile[64][65];
    int i = blockIdx.z;
    int k0 = blockIdx.y * 64, n0 = blockIdx.x * 64;
    int tid = threadIdx.x, c = tid & 63, rr = tid >> 6;
    const float* s = src + (size_t)i * srcLS;
    __bf16* dp = dst + (size_t)i * dstLS;
    for (int it = 0; it < 16; ++it) {
        int kl = it * 4 + rr;
        tile[kl][c] = s[(k0 + kl) * N + n0 + c];
    }
    __syncthreads();
    for (int it = 0; it < 16; ++it) {
        int nl = it * 4 + rr;
        dp[(size_t)(n0 + nl) * K + k0 + c] = (__bf16)tile[c][nl];
    }
}

__global__ void bias_gate_kernel(const float* __restrict__ b_in, const float* __restrict__ b_cond,
                                 float* __restrict__ bias) {
    int idx = blockIdx.x * 256 + threadIdx.x;   // 0..6143
    int i = idx >> 9, np = idx & 511;
    int phys = ((np >> 4) & 1) * 256 + (np >> 5) * 16 + (np & 15);
    bias[idx] = b_in[i * 512 + phys] + b_cond[i * 512 + phys];
}

// blocks 0..95: wfold[i][k][c] = sum_j w_res_skip[i][k][j] * w_end[j][c]  (i=11 uses w_res_last)
// block 96: outconst[c] = b_end[c] + (sum_i b_res_skip[i] + b_res_last) @ w_end
__global__ void wfold_kernel(const float* __restrict__ w_res, const float* __restrict__ w_res_last,
                             const float* __restrict__ w_end, const float* __restrict__ b_res,
                             const float* __restrict__ b_res_last, const float* __restrict__ b_end,
                             float* __restrict__ wfold, float* __restrict__ outconst) {
    if (blockIdx.x == 96) {
        __shared__ float red[256][8];
        int j = threadIdx.x;
        float bsum = b_res_last[j];
        for (int i = 0; i < 11; ++i) bsum += b_res[i * 512 + 256 + j];
        for (int c = 0; c < 8; ++c) red[j][c] = bsum * w_end[j * 8 + c];
        __syncthreads();
        if (j < 8) {
            float s = b_end[j];
            for (int t = 0; t < 256; ++t) s += red[t][j];
            outconst[j] = s;
        }
        return;
    }
    int idx = blockIdx.x * 256 + threadIdx.x;   // 0..24575
    int i = idx >> 11, rem = idx & 2047, k = rem >> 3, c = rem & 7;
    float s = 0.f;
    if (i < 11) {
        const float* wr = w_res + (size_t)(i * 256 + k) * 512 + 256;
        for (int j = 0; j < 256; ++j) s += wr[j] * w_end[j * 8 + c];
    } else {
        const float* wr = w_res_last + k * 256;
        for (int j = 0; j < 256; ++j) s += wr[j] * w_end[j * 8 + c];
    }
    wfold[idx] = s;
}

// ---------------- main GEMM kernels ----------------

// fused conv + cond + gate. 256x256 tile, 512 threads (8 waves, 2m x 4n),
// BK=32, ring of 4 LDS slots (128KB), global_load_lds staged 2 tiles ahead,
// counted s_waitcnt vmcnt (never 0 until tail), ONE raw s_barrier per k-tile,
// fragments register-pipelined one phase ahead (MFMA of phase p uses regs read
// in phase p-1; ds_reads overlap MFMA; lgkm waits are counted, not drains).
// In-row XOR swizzle (col ^= ((row>>1)&3)*8) pre-applied on global source.
// Grid: x = m (128), y = n (2); pair (x,0)/(x,1) same XCD.
__global__ __launch_bounds__(512, 2) void gate_kernel(
    const __bf16* __restrict__ started_pad, const __bf16* __restrict__ spect,
    const __bf16* __restrict__ Wg,     // layer base [512][1408]
    const float* __restrict__ bias,    // layer base [512] (interleaved order)
    __bf16* __restrict__ activated, int d) {
    // LDS: A slots s*8192 elems (s=0..3), B slots 32768 + s*8192. 65536 elems = 128KB.
    __shared__ __align__(16) __bf16 SMEM[65536];
    const int tid = threadIdx.x;
    const int m0 = blockIdx.x * 256;
    const int n0 = blockIdx.y * 256;
    const int padbase = ((m0 >> 12) << 13) + PAD + (m0 & 4095);
    const int wave = tid >> 6, lane = tid & 63;
    const int wr = wave >> 2, wc = wave & 3;          // 2 m-rows x 4 n-cols of waves
    const int quad = lane >> 4, l15 = lane & 15;

    // staging geometry: thread covers 16B at (row = op*128 + (tid>>2), col 16B-slot tid&3)
    const int srow = tid >> 2;                                        // 0..127
    const int scw = ((tid & 3) * 8) ^ (((tid >> 3) & 3) << 3);        // pre-swizzled col (elems)

    f32x4 acc[8][4];
    #pragma unroll
    for (int i = 0; i < 8; i++)
        #pragma unroll
        for (int j = 0; j < 4; j++) acc[i][j] = f32x4{0.f, 0.f, 0.f, 0.f};

    auto stageA = [&](int kt, int s) {
        const __bf16* g0;
        int rs;
        if (kt < 24) {                       // conv taps: 8 tiles per tap
            int tap = kt >> 3;
            int cb = (kt & 7) * 32;
            g0 = started_pad + (padbase + (tap - 1) * d) * 256 + cb + scw;
            rs = 256;
        } else {                             // cond: spect cols
            int cb = (kt - 24) * 32;
            g0 = spect + (size_t)m0 * 640 + cb + scw;
            rs = 640;
        }
        __bf16* As = SMEM + s * 8192;
        g2l16(g0 + srow * rs, As + tid * 8);
        g2l16(g0 + (128 + srow) * rs, As + 4096 + tid * 8);
    };
    auto stageB = [&](int kt, int s) {
        const __bf16* g0 = Wg + (size_t)(n0 + srow) * KG + kt * 32 + scw;
        __bf16* Bs = SMEM + 32768 + s * 8192;
        g2l16(g0, Bs + tid * 8);
        g2l16(g0 + 128 * KG, Bs + 4096 + tid * 8);
    };

    // prologue: tiles 0 and 1 staged; wait tile 0 (leave tile 1 in flight)
    stageA(0, 0); stageB(0, 0);
    stageA(1, 1); stageB(1, 1);
    asm volatile("s_waitcnt vmcnt(4)" ::: "memory");
    asm volatile("s_barrier" ::: "memory");

    bf16x8 a_cur[4], b_cur[4], b_nxt[4];
    {
        const __bf16* Asl = SMEM;
        const __bf16* Bsl = SMEM + 32768;
        #pragma unroll
        for (int f = 0; f < 4; ++f) {
            int ar = wr * 128 + f * 16 + l15;
            a_cur[f] = *(const bf16x8*)&Asl[ar * 32 + ((quad * 8) ^ (((ar >> 1) & 3) << 3))];
        }
        #pragma unroll
        for (int nf = 0; nf < 4; ++nf) {
            int br = wc * 64 + nf * 16 + l15;
            b_cur[nf] = *(const bf16x8*)&Bsl[br * 32 + ((quad * 8) ^ (((br >> 1) & 3) << 3))];
        }
    }

    for (int j = 0; j < 44; ++j) {
        const int s = j & 3;
        const int sn = (j + 1) & 3;
        const __bf16* Asl = SMEM + s * 8192;

        // ---- phase 0: stage A(j+2); read A(j, half1); confirm tile j+1; MFMA half0 ----
        if (j + 2 < 44) stageA(j + 2, (j + 2) & 3);
        bf16x8 a_nxt[4];
        #pragma unroll
        for (int f = 0; f < 4; ++f) {
            int ar = wr * 128 + 64 + f * 16 + l15;
            a_nxt[f] = *(const bf16x8*)&Asl[ar * 32 + ((quad * 8) ^ (((ar >> 1) & 3) << 3))];
        }
        if (j + 2 < 44) asm volatile("s_waitcnt vmcnt(2)" ::: "memory");
        else            asm volatile("s_waitcnt vmcnt(0)" ::: "memory");
        __builtin_amdgcn_s_setprio(1);
        #pragma unroll
        for (int f = 0; f < 4; ++f)
            #pragma unroll
            for (int nf = 0; nf < 4; ++nf)
                acc[f][nf] = __builtin_amdgcn_mfma_f32_16x16x32_bf16(a_cur[f], b_cur[nf], acc[f][nf], 0, 0, 0);
        __builtin_amdgcn_s_setprio(0);
        asm volatile("s_barrier" ::: "memory");   // slot j+1 now readable by all waves

        // ---- phase 1: stage B(j+2); read A(j+1, half0) + B(j+1); MFMA half1 ----
        if (j + 2 < 44) stageB(j + 2, (j + 2) & 3);
        if (j + 1 < 44) {
            const __bf16* Anl = SMEM + sn * 8192;
            const __bf16* Bnl = SMEM + 32768 + sn * 8192;
            #pragma unroll
            for (int f = 0; f < 4; ++f) {
                int ar = wr * 128 + f * 16 + l15;
                a_cur[f] = *(const bf16x8*)&Anl[ar * 32 + ((quad * 8) ^ (((ar >> 1) & 3) << 3))];
            }
            #pragma unroll
            for (int nf = 0; nf < 4; ++nf) {
                int br = wc * 64 + nf * 16 + l15;
                b_nxt[nf] = *(const bf16x8*)&Bnl[br * 32 + ((quad * 8) ^ (((br >> 1) & 3) << 3))];
            }
        }
        __builtin_amdgcn_s_setprio(1);
        #pragma unroll
        for (int f = 0; f < 4; ++f)
            #pragma unroll
            for (int nf = 0; nf < 4; ++nf)
                acc[4 + f][nf] = __builtin_amdgcn_mfma_f32_16x16x32_bf16(a_nxt[f], b_cur[nf], acc[4 + f][nf], 0, 0, 0);
        __builtin_amdgcn_s_setprio(0);
        if (j + 1 < 44) {
            #pragma unroll
            for (int nf = 0; nf < 4; ++nf) b_cur[nf] = b_nxt[nf];
        }
    }

    __syncthreads();   // drain everything before SMEM reuse

    // epilogue: gate, stage 256x128 activated channels in LDS (row stride 132), coalesced store.
    __bf16* tile = SMEM;   // 256*132 = 33792 elems <= 65536
    #pragma unroll
    for (int nj = 0; nj < 2; ++nj) {
        int colT = wc * 64 + nj * 32 + l15;
        float bt = bias[n0 + colT];
        float bs = bias[n0 + colT + 16];
        int chl = wc * 32 + nj * 16 + l15;
        #pragma unroll
        for (int mi = 0; mi < 8; ++mi) {
            #pragma unroll
            for (int reg = 0; reg < 4; ++reg) {
                int row = wr * 128 + mi * 16 + quad * 4 + reg;
                float xt = acc[mi][2 * nj][reg] + bt;
                float xs = acc[mi][2 * nj + 1][reg] + bs;
                float th = 2.f / (1.f + __expf(-2.f * xt)) - 1.f;
                float sg = 1.f / (1.f + __expf(-xs));
                tile[row * 132 + chl] = (__bf16)(th * sg);
            }
        }
    }
    __syncthreads();
    int chb = n0 >> 1;
    for (int pass = 0; pass < 8; ++pass) {
        int row = (tid >> 4) + 32 * pass;
        int seg = tid & 15;
        bf16x8 v = *(const bf16x8*)&tile[row * 132 + seg * 8];
        *(bf16x8*)&activated[(m0 + row) * 256 + chb + seg * 8] = v;
    }
}

// rs_res = activated @ Wr + b_res ; started_pad += rs_res (bf16 RMW)
// Grid (256,2): x = m (fast) so the reader of m-tile x sits on the XCD that produced it.
// Blocks with blockIdx.y==0 also run out += activated @ wfold via MFMA (bf16 wfold,
// 16-col B-extension in LDS; waves with wn==0 cover all 128 rows).
__global__ __launch_bounds__(256) void res_kernel(
    const __bf16* __restrict__ activated, const __bf16* __restrict__ Wr,  // [256][256]
    const float* __restrict__ b_res,      // layer base (first 256 cols used)
    const float* __restrict__ wfold,      // layer base [256][8] fp32
    const float* __restrict__ outconst,
    __bf16* __restrict__ started_pad, float* __restrict__ out, int initOut) {
    __shared__ __align__(16) __bf16 As[128 * 32];
    __shared__ __align__(16) __bf16 Bs[128 * 32];
    __shared__ __align__(16) __bf16 WfB[16 * 264];   // [col][k], cols 8..15 zero, padded stride
    const int tid = threadIdx.x;
    const int m0 = blockIdx.x * 128;
    const int n0 = blockIdx.y * 128;
    const int srow = tid >> 2;
    const int skq = (tid & 3) * 8;
    const int wave = tid >> 6, lane = tid & 63;
    const int wm = (wave >> 1) * 64, wn = (wave & 1) * 64;
    const int quad = lane >> 4, l15 = lane & 15;
    const bool doOut = (blockIdx.y == 0);
    const bool outWave = doOut && (wn == 0);

    f32x4 acc[4][4];
    for (int i = 0; i < 4; i++)
        for (int j = 0; j < 4; j++) acc[i][j] = f32x4{0.f, 0.f, 0.f, 0.f};
    f32x4 acc_o[4];
    for (int i = 0; i < 4; i++) acc_o[i] = f32x4{0.f, 0.f, 0.f, 0.f};

    const __bf16* Abase = activated + (m0 + srow) * 256 + skq;
    const __bf16* Bbase = Wr + (n0 + srow) * 256 + skq;

    if (doOut) {
        // stage wfold bf16 [16 cols][256 k] (cols 8..15 = 0)
        for (int t = 0; t < 16; ++t) {
            int e = t * 256 + tid;          // 0..4095
            int col = e >> 8, k = e & 255;
            WfB[col * 264 + k] = (col < 8) ? (__bf16)wfold[k * 8 + col] : (__bf16)0.f;
        }
    }

    for (int ks = 0; ks < 8; ++ks) {
        int kk = ks * 32;
        g2l16(Abase + kk, &As[srow * 32 + skq]);
        g2l16(Abase + kk + 64 * 256, &As[(64 + srow) * 32 + skq]);
        g2l16(Bbase + kk, &Bs[srow * 32 + skq]);
        g2l16(Bbase + kk + 64 * 256, &Bs[(64 + srow) * 32 + skq]);
        __syncthreads();
        bf16x8 a[4], b[4];
        for (int mi = 0; mi < 4; mi++) a[mi] = *(const bf16x8*)&As[(wm + mi * 16 + l15) * 32 + quad * 8];
        for (int ni = 0; ni < 4; ni++) b[ni] = *(const bf16x8*)&Bs[(wn + ni * 16 + l15) * 32 + quad * 8];
        for (int mi = 0; mi < 4; mi++)
            for (int ni = 0; ni < 4; ni++)
                acc[mi][ni] = __builtin_amdgcn_mfma_f32_16x16x32_bf16(a[mi], b[ni], acc[mi][ni], 0, 0, 0);
        if (outWave) {
            bf16x8 bx = *(const bf16x8*)&WfB[l15 * 264 + kk + quad * 8];
            for (int mi = 0; mi < 4; mi++)
                acc_o[mi] = __builtin_amdgcn_mfma_f32_16x16x32_bf16(a[mi], bx, acc_o[mi], 0, 0, 0);
        }
        __syncthreads();
    }

    for (int ni = 0; ni < 4; ++ni) {
        int col = n0 + wn + ni * 16 + l15;
        float bcol = b_res[col];
        for (int mi = 0; mi < 4; ++mi) {
            for (int reg = 0; reg < 4; ++reg) {
                int r = m0 + wm + mi * 16 + quad * 4 + reg;
                int pr = ((r >> 12) << 13) + PAD + (r & 4095);
                int idx = pr * 256 + col;
                float f = (float)started_pad[idx] + acc[mi][ni][reg] + bcol;
                started_pad[idx] = (__bf16)f;
            }
        }
    }
    if (outWave && l15 < 8) {
        for (int mi = 0; mi < 4; ++mi) {
            for (int reg = 0; reg < 4; ++reg) {
                int r = m0 + wm + mi * 16 + quad * 4 + reg;
                float base = initOut ? outconst[l15] : out[r * 8 + l15];
                out[r * 8 + l15] = base + acc_o[mi][reg];
            }
        }
    }
}

// last layer: out += activated @ wfold[11]  (no res half). Grid x = m (XCD-aligned).
__global__ __launch_bounds__(256) void outacc_kernel(
    const __bf16* __restrict__ activated, const float* __restrict__ wfold,
    float* __restrict__ out) {
    __shared__ __align__(16) float Wf[2048];
    int tid = threadIdx.x;
    ((float4*)Wf)[tid] = ((const float4*)wfold)[tid];
    ((float4*)Wf)[256 + tid] = ((const float4*)wfold)[256 + tid];
    __syncthreads();
    int row2 = tid >> 1, half = tid & 1;
    int r = blockIdx.x * 128 + row2;
    const bf16x8* ap = (const bf16x8*)(activated + r * 256);
    const float4* wf = (const float4*)Wf;
    float ox = 0.f, oy = 0.f, oz = 0.f, ow = 0.f;
    for (int c8 = 0; c8 < 32; ++c8) {
        bf16x8 av = ap[c8];
        for (int e = 0; e < 8; ++e) {
            float a = (float)av[e];
            float4 w = wf[(c8 * 8 + e) * 2 + half];
            ox += a * w.x; oy += a * w.y; oz += a * w.z; ow += a * w.w;
        }
    }
    float4* op = (float4*)&out[r * 8 + half * 4];
    float4 o = *op;
    o.x += ox; o.y += oy; o.z += oz; o.w += ow;
    *op = o;
}

// ---------------- launch ----------------

extern "C" void kernel_launch(void* const* d_in, const int* in_sizes, int n_in,
                              void* d_out, int out_size, void* d_ws, size_t ws_size,
                              hipStream_t stream) {
    const float* audio      = (const float*)d_in[0];
    const float* spect      = (const float*)d_in[1];
    const float* w_start    = (const float*)d_in[2];
    const float* b_start    = (const float*)d_in[3];
    const float* w_in       = (const float*)d_in[4];
    const float* b_in       = (const float*)d_in[5];
    const float* w_cond     = (const float*)d_in[6];
    const float* b_cond     = (const float*)d_in[7];
    const float* w_res      = (const float*)d_in[8];
    const float* b_res      = (const float*)d_in[9];
    const float* w_res_last = (const float*)d_in[10];
    const float* b_res_last = (const float*)d_in[11];
    const float* w_end      = (const float*)d_in[12];
    const float* b_end      = (const float*)d_in[13];
    float* out = (float*)d_out;

    char* ws = (char*)d_ws;
    __bf16* started_pad = (__bf16*)ws; ws += 33554432;   // 65536 x 256 bf16 (padded)
    __bf16* activated   = (__bf16*)ws; ws += 16777216;   // 32768 x 256 bf16
    __bf16* spect_bf    = (__bf16*)ws; ws += 41943040;   // 32768 x 640 bf16
    __bf16* Wg          = (__bf16*)ws; ws += 17301504;   // 12 x 512 x 1408 bf16
    __bf16* Wr          = (__bf16*)ws; ws += 1441792;    // 11 x 256 x 256 bf16 (res half, [n][k])
    float*  wfold       = (float*)ws;  ws += 98304;      // 12 x 256 x 8 f32
    float*  biasg       = (float*)ws;  ws += 24576;      // 12 x 512 f32
    float*  outconst    = (float*)ws;  ws += 256;        // 8 f32

    init_started_kernel<<<dim3(16384), 256, 0, stream>>>(audio, w_start, b_start, started_pad);
    cvt_bf16_kernel<<<dim3(20480), 256, 0, stream>>>((const float4*)spect, (bf16x4*)spect_bf, 5242880);
    transpose_gate<<<dim3(8, 22, 12), 256, 0, stream>>>(w_in, w_cond, Wg);
    transpose_kn<<<dim3(4, 4, 11), 256, 0, stream>>>(w_res, Wr, 256, 512, 256 * 512, 256 * 256);
    bias_gate_kernel<<<dim3(24), 256, 0, stream>>>(b_in, b_cond, biasg);
    wfold_kernel<<<dim3(97), 256, 0, stream>>>(w_res, w_res_last, w_end, b_res, b_res_last, b_end,
                                               wfold, outconst);

    for (int i = 0; i < 12; ++i) {
        gate_kernel<<<dim3(128, 2), 512, 0, stream>>>(
            started_pad, spect_bf, Wg + (size_t)i * 512 * KG, biasg + i * 512, activated, 1 << i);
        if (i < 11) {
            res_kernel<<<dim3(256, 2), 256, 0, stream>>>(
                activated, Wr + (size_t)i * 256 * 256, b_res + i * 512,
                wfold + i * 2048, outconst, started_pad, out, i == 0 ? 1 : 0);
        } else {
            outacc_kernel<<<dim3(256), 256, 0, stream>>>(activated, wfold + 11 * 2048, out);
        }
    }
}